// Round 1
// baseline (1364.193 us; speedup 1.0000x reference)
//
#include <hip/hip_runtime.h>
#include <stdint.h>

#define NB 64
#define NH 32
#define KCTX 4096
#define HID 7168
#define QLORA 1536
#define KVL 512
#define DROPE 64
#define DTOT 576
#define HS 192
#define VD 128
#define NSPLIT 8
#define KSPAN 512          // KCTX/NSPLIT
#define TK 32
#define NTILE 16           // KSPAN/TK
#define SM_SCALE 0.07216878364870323f  // 1/sqrt(192)
#define NEGINF -3.0e38f

static __device__ __forceinline__ float bf_lo(unsigned u){ union{unsigned i;float f;}x; x.i=u<<16; return x.f; }
static __device__ __forceinline__ float bf_hi(unsigned u){ union{unsigned i;float f;}x; x.i=u&0xffff0000u; return x.f; }
static __device__ __forceinline__ unsigned short f2bf(float f){
    union{float f;unsigned i;}x; x.f=f;
    unsigned r = x.i + 0x7fffu + ((x.i>>16)&1u);
    return (unsigned short)(r>>16);
}

// ---------- generic split-K skinny GEMM: P[s][b][n] = sum_{k in 256-chunk s} A[b][k]*W[k][n]
__global__ __launch_bounds__(256) void gemm64_part(const float* __restrict__ A,
        const float* __restrict__ Wm, float* __restrict__ P, int N, int K)
{
    const int t = threadIdx.x;
    const int n = blockIdx.x*256 + t;
    const int s = blockIdx.y;
    const int k0 = s*256;
    __shared__ float a_s[64*128];
    float acc[64];
#pragma unroll
    for (int i=0;i<64;++i) acc[i]=0.f;
    for (int c=0;c<2;++c){
        __syncthreads();
#pragma unroll
        for (int i=0;i<32;++i){
            int idx = i*256 + t;
            int bb = idx>>7, kk = idx&127;
            a_s[idx] = A[(size_t)bb*K + k0 + c*128 + kk];
        }
        __syncthreads();
        if (n < N){
            const float* wp = Wm + (size_t)(k0 + c*128)*N + n;
            for (int kk0=0; kk0<128; kk0+=4){
                float w0 = wp[(size_t)(kk0+0)*N];
                float w1 = wp[(size_t)(kk0+1)*N];
                float w2 = wp[(size_t)(kk0+2)*N];
                float w3 = wp[(size_t)(kk0+3)*N];
#pragma unroll
                for (int bb=0;bb<64;++bb){
                    const float4 a = *(const float4*)(a_s + bb*128 + kk0);
                    acc[bb] = fmaf(a.x,w0,fmaf(a.y,w1,fmaf(a.z,w2,fmaf(a.w,w3,acc[bb]))));
                }
            }
        }
    }
    if (n < N){
#pragma unroll
        for (int bb=0;bb<64;++bb) P[((size_t)s*64+bb)*N + n] = acc[bb];
    }
}

// ---------- reduce 28 partials + rmsnorm -> q_c[64][1536]
__global__ __launch_bounds__(256) void reduce_rms_qc(const float* __restrict__ P,
        const float* __restrict__ w, float* __restrict__ out)
{
    const int b = blockIdx.x, t = threadIdx.x;
    float v[6]; float ss = 0.f;
#pragma unroll
    for (int j=0;j<6;++j){
        int n = j*256 + t;
        float s = 0.f;
        for (int sp=0; sp<28; ++sp) s += P[((size_t)sp*64+b)*1536 + n];
        v[j] = s; ss += s*s;
    }
    __shared__ float red[4];
#pragma unroll
    for (int off=32; off>=1; off>>=1) ss += __shfl_xor(ss, off, 64);
    if ((t&63)==0) red[t>>6] = ss;
    __syncthreads();
    float tot = red[0]+red[1]+red[2]+red[3];
    float rs = rsqrtf(tot/1536.f + 1e-6f);
#pragma unroll
    for (int j=0;j<6;++j){
        int n = j*256+t;
        out[(size_t)b*1536 + n] = v[j]*rs*w[n];
    }
}

// ---------- generic partial reduce: out[b*N+n] = sum_s P[s][b][n]
__global__ __launch_bounds__(256) void reduce_sum(const float* __restrict__ P,
        float* __restrict__ out, int S, int N)
{
    int i = blockIdx.x*256 + threadIdx.x;
    int b = i / N, n = i - b*N;
    float s = 0.f;
    for (int sp=0; sp<S; ++sp) s += P[((size_t)sp*64+b)*N + n];
    out[i] = s;
}

// ---------- reduce ckv partials + rmsnorm(512) + rope(last 64) -> latent[64][576]
__global__ __launch_bounds__(256) void reduce_kv_rope(const float* __restrict__ P,
        const float* __restrict__ w, const float* __restrict__ cosb, const float* __restrict__ sinb,
        float* __restrict__ latent)
{
    const int b = blockIdx.x, t = threadIdx.x;
    __shared__ float vals[576];
    __shared__ float red[4];
    float ss = 0.f;
    for (int j=0;j<3;++j){
        int n = j*256+t;
        if (n < 576){
            float s=0.f;
            for (int sp=0;sp<28;++sp) s += P[((size_t)sp*64+b)*576 + n];
            vals[n]=s;
            if (n<512) ss += s*s;
        }
    }
#pragma unroll
    for (int off=32; off>=1; off>>=1) ss += __shfl_xor(ss, off, 64);
    if ((t&63)==0) red[t>>6]=ss;
    __syncthreads();
    float tot = red[0]+red[1]+red[2]+red[3];
    float rs = rsqrtf(tot/512.f + 1e-6f);
    for (int j=0;j<3;++j){
        int n = j*256+t;
        if (n<576){
            float o;
            if (n < 512) o = vals[n]*rs*w[n];
            else if (n < 544){ int i=n-512; o = vals[512+2*i]*cosb[b*32+i] - vals[513+2*i]*sinb[b*32+i]; }
            else            { int i=n-544; o = vals[513+2*i]*cosb[b*32+i] + vals[512+2*i]*sinb[b*32+i]; }
            latent[(size_t)b*576 + n] = o;
        }
    }
}

// ---------- ql_nope: query[b][h][r] = sum_n q[b][h][n]*w_uk_t[h][n][r]   (r<512)
__global__ __launch_bounds__(256) void qlnope_query(const float* __restrict__ q,
        const float* __restrict__ wukt, float* __restrict__ query)
{
    const int h = blockIdx.x;
    const int t = threadIdx.x;
    const int r = blockIdx.y*256 + t;
    __shared__ float qn[64*128];
    float acc[64];
#pragma unroll
    for (int i=0;i<64;++i) acc[i]=0.f;
#pragma unroll
    for (int i=0;i<32;++i){
        int idx = i*256+t;
        int bb = idx>>7, nn = idx&127;
        qn[idx] = q[((size_t)bb*32+h)*192 + nn];
    }
    __syncthreads();
    const float* wp = wukt + (size_t)h*128*512 + r;
    for (int n0=0;n0<128;n0+=4){
        float w0 = wp[(size_t)(n0+0)*512];
        float w1 = wp[(size_t)(n0+1)*512];
        float w2 = wp[(size_t)(n0+2)*512];
        float w3 = wp[(size_t)(n0+3)*512];
#pragma unroll
        for (int bb=0;bb<64;++bb){
            const float4 a = *(const float4*)(qn + bb*128 + n0);
            acc[bb] = fmaf(a.x,w0,fmaf(a.y,w1,fmaf(a.z,w2,fmaf(a.w,w3,acc[bb]))));
        }
    }
#pragma unroll
    for (int bb=0;bb<64;++bb) query[((size_t)bb*32+h)*576 + r] = acc[bb];
}

// ---------- rope for q_pe -> query[b][h][512..575]
__global__ __launch_bounds__(256) void rope_q(const float* __restrict__ q,
        const float* __restrict__ cosb, const float* __restrict__ sinb, float* __restrict__ query)
{
    const int b = blockIdx.x, t = threadIdx.x;
#pragma unroll
    for (int j=0;j<4;++j){
        int item = j*256+t;
        int h = item>>5, i = item&31;
        const float* qp = q + ((size_t)b*32+h)*192 + 128;
        float x1 = qp[2*i], x2 = qp[2*i+1];
        float c = cosb[b*32+i], s = sinb[b*32+i];
        float* o = query + ((size_t)b*32+h)*576;
        o[512+i] = x1*c - x2*s;
        o[544+i] = x2*c + x1*s;
    }
}

// ---------- flash decode attention, fp32 VALU, bf16 K/V tile in LDS
__global__ __launch_bounds__(256,1) void attn_flash(const float* __restrict__ query,
        const float* __restrict__ kv, const float* __restrict__ latent,
        const int* __restrict__ slots, const int* __restrict__ seq_lens,
        float* __restrict__ Opart, float* __restrict__ Mpart, float* __restrict__ Lpart)
{
    extern __shared__ char smem[];
    float* q_s = (float*)smem;                               // 32*576 f32 = 73728 B
    unsigned short* ct = (unsigned short*)(smem + 73728);    // 2*32*576 bf16 = 73728 B
    float* p_s = (float*)(smem + 147456);                    // 32*32 f32 = 4096 B

    const int b = blockIdx.y, sp = blockIdx.x;
    const int tid = threadIdx.x;
    const int w = tid>>6, l = tid&63;
    const int half = l>>5, kk = l&31;
    const int hb4 = w*8 + half*4;       // this lane's 4 scoring heads
    const int seqlen = seq_lens[b];
    const int slot = slots[b];
    const int k0 = sp*KSPAN;

    // stage q (linear block copy)
    {
        const float* src = query + (size_t)b*32*576;
#pragma unroll
        for (int j=0;j<18;++j){
            int e = j*1024 + tid*4;
            *(float4*)(q_s + e) = *(const float4*)(src + e);
        }
    }

    float4 st[18];
    auto load_tile = [&](int tt){
#pragma unroll
        for (int j=0;j<18;++j){
            int e = j*1024 + tid*4;
            int row = e/576; int col = e - row*576;
            int gk = k0 + tt*TK + row;
            const float* src = (gk==slot) ? (latent + (size_t)b*576 + col)
                                          : (kv + ((size_t)b*KCTX + gk)*576 + col);
            st[j] = *(const float4*)src;
        }
    };
    auto write_tile = [&](int buf){
#pragma unroll
        for (int j=0;j<18;++j){
            int e = j*1024 + tid*4;
            int row = e/576; int col = e - row*576;
            int c2 = col ^ ((row&7)<<3);          // XOR swizzle (16B granular in bytes)
            unsigned short* d = ct + buf*18432 + row*576 + c2;
            ushort4 u;
            u.x=f2bf(st[j].x); u.y=f2bf(st[j].y); u.z=f2bf(st[j].z); u.w=f2bf(st[j].w);
            *(ushort4*)d = u;
        }
    };

    float Oacc[8][8];
#pragma unroll
    for (int i=0;i<8;++i)
#pragma unroll
        for (int j=0;j<8;++j) Oacc[i][j]=0.f;
    float m_reg[4], l_reg[4];
#pragma unroll
    for (int i=0;i<4;++i){ m_reg[i]=NEGINF; l_reg[i]=0.f; }

    load_tile(0);
    write_tile(0);
    __syncthreads();

    for (int tt=0; tt<NTILE; ++tt){
        const int buf = tt&1;
        const bool more = (tt+1 < NTILE);
        if (more) load_tile(tt+1);

        // ---- QK^T : lane scores its kk row against 4 heads
        float sacc[4] = {0.f,0.f,0.f,0.f};
        const unsigned short* cb = ct + buf*18432 + kk*576;
        const int sw = (kk&7)<<3;
        for (int d0=0; d0<576; d0+=8){
            const uint4 cc = *(const uint4*)(cb + (d0 ^ sw));
            float c0=bf_lo(cc.x), c1=bf_hi(cc.x), c2=bf_lo(cc.y), c3=bf_hi(cc.y);
            float c4=bf_lo(cc.z), c5=bf_hi(cc.z), c6=bf_lo(cc.w), c7=bf_hi(cc.w);
#pragma unroll
            for (int hh=0;hh<4;++hh){
                const float* qp = q_s + (hb4+hh)*576 + d0;
                float4 qa = *(const float4*)qp;
                float4 qb = *(const float4*)(qp+4);
                float sv = sacc[hh];
                sv = fmaf(qa.x,c0,sv); sv = fmaf(qa.y,c1,sv);
                sv = fmaf(qa.z,c2,sv); sv = fmaf(qa.w,c3,sv);
                sv = fmaf(qb.x,c4,sv); sv = fmaf(qb.y,c5,sv);
                sv = fmaf(qb.z,c6,sv); sv = fmaf(qb.w,c7,sv);
                sacc[hh] = sv;
            }
        }
        const int gk = k0 + tt*TK + kk;
        const bool valid = (gk < seqlen);

        // ---- online softmax (per h, reduce over 32 lanes of the half-wave)
        float p[4], alpha[4];
#pragma unroll
        for (int hh=0;hh<4;++hh){
            float sv = valid ? sacc[hh]*SM_SCALE : NEGINF;
            float tm = sv;
            tm = fmaxf(tm, __shfl_xor(tm,1));
            tm = fmaxf(tm, __shfl_xor(tm,2));
            tm = fmaxf(tm, __shfl_xor(tm,4));
            tm = fmaxf(tm, __shfl_xor(tm,8));
            tm = fmaxf(tm, __shfl_xor(tm,16));
            float mnew = fmaxf(m_reg[hh], tm);
            alpha[hh] = __expf(m_reg[hh] - mnew);
            m_reg[hh] = mnew;
            float pv = valid ? __expf(sv - mnew) : 0.f;
            p[hh] = pv;
            float ps = pv;
            ps += __shfl_xor(ps,1);
            ps += __shfl_xor(ps,2);
            ps += __shfl_xor(ps,4);
            ps += __shfl_xor(ps,8);
            ps += __shfl_xor(ps,16);
            l_reg[hh] = l_reg[hh]*alpha[hh] + ps;
            p_s[(hb4+hh)*32 + kk] = pv;
        }
        // alpha exchange across halves + O rescale
        float alo[4];
#pragma unroll
        for (int hh=0;hh<4;++hh) alo[hh] = __shfl_xor(alpha[hh],32);
#pragma unroll
        for (int h2=0;h2<8;++h2){
            float a = ((h2>>2)==half) ? alpha[h2&3] : alo[h2&3];
#pragma unroll
            for (int rr=0;rr<8;++rr) Oacc[h2][rr] *= a;
        }

        // ---- PV : lane owns 8 consecutive r, all 8 wave-heads
        const int rbase = l*8;
        for (int k2=0;k2<TK;++k2){
            const uint4 cc = *(const uint4*)(ct + buf*18432 + k2*576 + (rbase ^ ((k2&7)<<3)));
            float c0=bf_lo(cc.x), c1=bf_hi(cc.x), c2=bf_lo(cc.y), c3=bf_hi(cc.y);
            float c4=bf_lo(cc.z), c5=bf_hi(cc.z), c6=bf_lo(cc.w), c7=bf_hi(cc.w);
#pragma unroll
            for (int hh=0;hh<8;++hh){
                float pv = p_s[(w*8+hh)*32 + k2];
                Oacc[hh][0] += pv*c0; Oacc[hh][1] += pv*c1;
                Oacc[hh][2] += pv*c2; Oacc[hh][3] += pv*c3;
                Oacc[hh][4] += pv*c4; Oacc[hh][5] += pv*c5;
                Oacc[hh][6] += pv*c6; Oacc[hh][7] += pv*c7;
            }
        }
        __syncthreads();
        if (more){ write_tile(buf^1); __syncthreads(); }
    }

    // ---- write partials
    const int obase = (b*NSPLIT+sp)*32;
#pragma unroll
    for (int hh=0;hh<8;++hh){
        float4 v0 = make_float4(Oacc[hh][0],Oacc[hh][1],Oacc[hh][2],Oacc[hh][3]);
        float4 v1 = make_float4(Oacc[hh][4],Oacc[hh][5],Oacc[hh][6],Oacc[hh][7]);
        float* op = Opart + ((size_t)(obase + w*8+hh))*512 + l*8;
        *(float4*)op = v0; *(float4*)(op+4) = v1;
    }
    float mo[4], lo4[4];
#pragma unroll
    for (int hh=0;hh<4;++hh){ mo[hh]=__shfl_xor(m_reg[hh],32); lo4[hh]=__shfl_xor(l_reg[hh],32); }
    if (l==0){
#pragma unroll
        for (int hh=0;hh<4;++hh){
            Mpart[obase + w*8 + hh]     = m_reg[hh];
            Mpart[obase + w*8 + 4 + hh] = mo[hh];
            Lpart[obase + w*8 + hh]     = l_reg[hh];
            Lpart[obase + w*8 + 4 + hh] = lo4[hh];
        }
    }
}

// ---------- merge NSPLIT flash partials -> attn[b][h][512]
__global__ __launch_bounds__(256) void merge_attn(const float* __restrict__ Opart,
        const float* __restrict__ Mpart, const float* __restrict__ Lpart, float* __restrict__ attn)
{
    const int bh = blockIdx.x;
    const int b = bh>>5, h = bh&31;
    const int t = threadIdx.x;
    float m[NSPLIT], lw[NSPLIT];
    float M = NEGINF;
#pragma unroll
    for (int s=0;s<NSPLIT;++s){ m[s] = Mpart[(b*NSPLIT+s)*32 + h]; M = fmaxf(M,m[s]); }
    float L = 0.f;
#pragma unroll
    for (int s=0;s<NSPLIT;++s){ lw[s] = __expf(m[s]-M); L += lw[s]*Lpart[(b*NSPLIT+s)*32+h]; }
    float inv = 1.f/L;
#pragma unroll
    for (int j=0;j<2;++j){
        int r = j*256+t;
        float o = 0.f;
#pragma unroll
        for (int s=0;s<NSPLIT;++s)
            o += lw[s]*Opart[((size_t)((b*NSPLIT+s)*32) + h)*512 + r];
        attn[((size_t)b*32+h)*512 + r] = o*inv;
    }
}

// ---------- out[b][h*128+v] = sum_r attn[b][h][r]*w_uv[h][r][v]
__global__ __launch_bounds__(128) void av_uv(const float* __restrict__ attn,
        const float* __restrict__ wuv, float* __restrict__ ao)
{
    const int h = blockIdx.x, bg = blockIdx.y, t = threadIdx.x;
    __shared__ float a_s[8*512];
#pragma unroll
    for (int i=0;i<32;++i){
        int idx = i*128+t;
        int bb = idx>>9, rr = idx&511;
        a_s[idx] = attn[((size_t)(bg*8+bb)*32 + h)*512 + rr];
    }
    __syncthreads();
    float acc[8];
#pragma unroll
    for (int i=0;i<8;++i) acc[i]=0.f;
    const float* wp = wuv + (size_t)h*512*128 + t;
    for (int r0=0;r0<512;r0+=4){
        float w0 = wp[(size_t)(r0+0)*128];
        float w1 = wp[(size_t)(r0+1)*128];
        float w2 = wp[(size_t)(r0+2)*128];
        float w3 = wp[(size_t)(r0+3)*128];
#pragma unroll
        for (int bb=0;bb<8;++bb){
            const float4 a = *(const float4*)(a_s + bb*512 + r0);
            acc[bb] = fmaf(a.x,w0,fmaf(a.y,w1,fmaf(a.z,w2,fmaf(a.w,w3,acc[bb]))));
        }
    }
#pragma unroll
    for (int bb=0;bb<8;++bb) ao[(size_t)(bg*8+bb)*4096 + h*128 + t] = acc[bb];
}

extern "C" void kernel_launch(void* const* d_in, const int* in_sizes, int n_in,
                              void* d_out, int out_size, void* d_ws, size_t ws_size,
                              hipStream_t stream)
{
    const float* hidden = (const float*)d_in[0];
    const float* cosb   = (const float*)d_in[1];
    const float* sinb   = (const float*)d_in[2];
    const float* kv     = (const float*)d_in[3];
    const float* w_q_a  = (const float*)d_in[4];
    const float* q_ln   = (const float*)d_in[5];
    const float* w_q_b  = (const float*)d_in[6];
    const float* w_kv_a = (const float*)d_in[7];
    const float* kv_ln  = (const float*)d_in[8];
    const float* w_uk_t = (const float*)d_in[9];
    const float* w_uv   = (const float*)d_in[10];
    const float* w_o    = (const float*)d_in[11];
    const int* slots    = (const int*)d_in[12];
    const int* seqlens  = (const int*)d_in[13];
    float* out = (float*)d_out;

    float* W = (float*)d_ws;
    float* P      = W;                  // 8,388,608 f32 (partials; aliases Opart)
    float* q_c    = W + 8388608;        // 98,304
    float* q      = W + 8486912;        // 393,216
    float* latent = W + 8880128;        // 36,864
    float* query  = W + 8916992;        // 1,179,648
    float* Mp     = W + 10096640;       // 16,384
    float* Lp     = W + 10113024;       // 16,384
    float* attn   = W + 10129408;       // 1,048,576
    float* ao     = W + 11177984;       // 262,144

    hipLaunchKernelGGL(gemm64_part, dim3(6,28), dim3(256), 0, stream, hidden, w_q_a, P, 1536, 7168);
    hipLaunchKernelGGL(reduce_rms_qc, dim3(64), dim3(256), 0, stream, P, q_ln, q_c);
    hipLaunchKernelGGL(gemm64_part, dim3(24,6), dim3(256), 0, stream, q_c, w_q_b, P, 6144, 1536);
    hipLaunchKernelGGL(reduce_sum, dim3(1536), dim3(256), 0, stream, P, q, 6, 6144);
    hipLaunchKernelGGL(gemm64_part, dim3(3,28), dim3(256), 0, stream, hidden, w_kv_a, P, 576, 7168);
    hipLaunchKernelGGL(reduce_kv_rope, dim3(64), dim3(256), 0, stream, P, kv_ln, cosb, sinb, latent);
    hipLaunchKernelGGL(qlnope_query, dim3(32,2), dim3(256), 0, stream, q, w_uk_t, query);
    hipLaunchKernelGGL(rope_q, dim3(64), dim3(256), 0, stream, q, cosb, sinb, query);
    hipLaunchKernelGGL(attn_flash, dim3(NSPLIT,64), dim3(256), 151552, stream,
                       query, kv, latent, slots, seqlens, P, Mp, Lp);
    hipLaunchKernelGGL(merge_attn, dim3(2048), dim3(256), 0, stream, P, Mp, Lp, attn);
    hipLaunchKernelGGL(av_uv, dim3(32,8), dim3(128), 0, stream, attn, w_uv, ao);
    hipLaunchKernelGGL(gemm64_part, dim3(28,16), dim3(256), 0, stream, ao, w_o, P, 7168, 4096);
    hipLaunchKernelGGL(reduce_sum, dim3(1792), dim3(256), 0, stream, P, out, 16, 7168);
}

// Round 2
// 899.621 us; speedup vs baseline: 1.5164x; 1.5164x over previous
//
#include <hip/hip_runtime.h>
#include <stdint.h>

#define NB 64
#define NH 32
#define KCTX 4096
#define HID 7168
#define QLORA 1536
#define KVL 512
#define DTOT 576
#define NSPLIT 8
#define SM_SCALE 0.07216878364870323f  // 1/sqrt(192)
#define NEGINF (-3.0e38f)

typedef __attribute__((ext_vector_type(4))) float f32x4;
typedef __attribute__((ext_vector_type(8))) __bf16 bf16x8;

static __device__ __forceinline__ unsigned short f2bf(float f){
    union{float f;unsigned i;}x; x.f=f;
    unsigned r = x.i + 0x7fffu + ((x.i>>16)&1u);
    return (unsigned short)(r>>16);
}
static __device__ __forceinline__ unsigned pack2(float a, float b){
    return (unsigned)f2bf(a) | ((unsigned)f2bf(b)<<16);
}

// ---------- generic split-K skinny GEMM: P[s][b][n] = sum_{k in 256-chunk s} A[b][k]*W[k][n]
__global__ __launch_bounds__(256) void gemm64_part(const float* __restrict__ A,
        const float* __restrict__ Wm, float* __restrict__ P, int N, int K)
{
    const int t = threadIdx.x;
    const int n = blockIdx.x*256 + t;
    const int s = blockIdx.y;
    const int k0 = s*256;
    __shared__ float a_s[64*128];
    float acc[64];
#pragma unroll
    for (int i=0;i<64;++i) acc[i]=0.f;
    for (int c=0;c<2;++c){
        __syncthreads();
#pragma unroll
        for (int i=0;i<32;++i){
            int idx = i*256 + t;
            int bb = idx>>7, kk = idx&127;
            a_s[idx] = A[(size_t)bb*K + k0 + c*128 + kk];
        }
        __syncthreads();
        if (n < N){
            const float* wp = Wm + (size_t)(k0 + c*128)*N + n;
            for (int kk0=0; kk0<128; kk0+=4){
                float w0 = wp[(size_t)(kk0+0)*N];
                float w1 = wp[(size_t)(kk0+1)*N];
                float w2 = wp[(size_t)(kk0+2)*N];
                float w3 = wp[(size_t)(kk0+3)*N];
#pragma unroll
                for (int bb=0;bb<64;++bb){
                    const float4 a = *(const float4*)(a_s + bb*128 + kk0);
                    acc[bb] = fmaf(a.x,w0,fmaf(a.y,w1,fmaf(a.z,w2,fmaf(a.w,w3,acc[bb]))));
                }
            }
        }
    }
    if (n < N){
#pragma unroll
        for (int bb=0;bb<64;++bb) P[((size_t)s*64+bb)*N + n] = acc[bb];
    }
}

// ---------- reduce 28 partials + rmsnorm -> q_c[64][1536]
__global__ __launch_bounds__(256) void reduce_rms_qc(const float* __restrict__ P,
        const float* __restrict__ w, float* __restrict__ out)
{
    const int b = blockIdx.x, t = threadIdx.x;
    float v[6]; float ss = 0.f;
#pragma unroll
    for (int j=0;j<6;++j){
        int n = j*256 + t;
        float s = 0.f;
        for (int sp=0; sp<28; ++sp) s += P[((size_t)sp*64+b)*1536 + n];
        v[j] = s; ss += s*s;
    }
    __shared__ float red[4];
#pragma unroll
    for (int off=32; off>=1; off>>=1) ss += __shfl_xor(ss, off, 64);
    if ((t&63)==0) red[t>>6] = ss;
    __syncthreads();
    float tot = red[0]+red[1]+red[2]+red[3];
    float rs = rsqrtf(tot/1536.f + 1e-6f);
#pragma unroll
    for (int j=0;j<6;++j){
        int n = j*256+t;
        out[(size_t)b*1536 + n] = v[j]*rs*w[n];
    }
}

// ---------- generic partial reduce: out[b*N+n] = sum_s P[s][b][n]
__global__ __launch_bounds__(256) void reduce_sum(const float* __restrict__ P,
        float* __restrict__ out, int S, int N)
{
    int i = blockIdx.x*256 + threadIdx.x;
    int b = i / N, n = i - b*N;
    float s = 0.f;
    for (int sp=0; sp<S; ++sp) s += P[((size_t)sp*64+b)*N + n];
    out[i] = s;
}

// ---------- reduce ckv partials + rmsnorm(512) + rope(last 64) -> latent[64][576]
__global__ __launch_bounds__(256) void reduce_kv_rope(const float* __restrict__ P,
        const float* __restrict__ w, const float* __restrict__ cosb, const float* __restrict__ sinb,
        float* __restrict__ latent)
{
    const int b = blockIdx.x, t = threadIdx.x;
    __shared__ float vals[576];
    __shared__ float red[4];
    float ss = 0.f;
    for (int j=0;j<3;++j){
        int n = j*256+t;
        if (n < 576){
            float s=0.f;
            for (int sp=0;sp<28;++sp) s += P[((size_t)sp*64+b)*576 + n];
            vals[n]=s;
            if (n<512) ss += s*s;
        }
    }
#pragma unroll
    for (int off=32; off>=1; off>>=1) ss += __shfl_xor(ss, off, 64);
    if ((t&63)==0) red[t>>6]=ss;
    __syncthreads();
    float tot = red[0]+red[1]+red[2]+red[3];
    float rs = rsqrtf(tot/512.f + 1e-6f);
    for (int j=0;j<3;++j){
        int n = j*256+t;
        if (n<576){
            float o;
            if (n < 512) o = vals[n]*rs*w[n];
            else if (n < 544){ int i=n-512; o = vals[512+2*i]*cosb[b*32+i] - vals[513+2*i]*sinb[b*32+i]; }
            else            { int i=n-544; o = vals[513+2*i]*cosb[b*32+i] + vals[512+2*i]*sinb[b*32+i]; }
            latent[(size_t)b*576 + n] = o;
        }
    }
}

// ---------- ql_nope: query[b][h][r] = sum_n q[b][h][n]*w_uk_t[h][n][r]   (r<512)
__global__ __launch_bounds__(256) void qlnope_query(const float* __restrict__ q,
        const float* __restrict__ wukt, float* __restrict__ query)
{
    const int h = blockIdx.x;
    const int t = threadIdx.x;
    const int r = blockIdx.y*256 + t;
    __shared__ float qn[64*128];
    float acc[64];
#pragma unroll
    for (int i=0;i<64;++i) acc[i]=0.f;
#pragma unroll
    for (int i=0;i<32;++i){
        int idx = i*256+t;
        int bb = idx>>7, nn = idx&127;
        qn[idx] = q[((size_t)bb*32+h)*192 + nn];
    }
    __syncthreads();
    const float* wp = wukt + (size_t)h*128*512 + r;
    for (int n0=0;n0<128;n0+=4){
        float w0 = wp[(size_t)(n0+0)*512];
        float w1 = wp[(size_t)(n0+1)*512];
        float w2 = wp[(size_t)(n0+2)*512];
        float w3 = wp[(size_t)(n0+3)*512];
#pragma unroll
        for (int bb=0;bb<64;++bb){
            const float4 a = *(const float4*)(qn + bb*128 + n0);
            acc[bb] = fmaf(a.x,w0,fmaf(a.y,w1,fmaf(a.z,w2,fmaf(a.w,w3,acc[bb]))));
        }
    }
#pragma unroll
    for (int bb=0;bb<64;++bb) query[((size_t)bb*32+h)*576 + r] = acc[bb];
}

// ---------- rope for q_pe -> query[b][h][512..575]
__global__ __launch_bounds__(256) void rope_q(const float* __restrict__ q,
        const float* __restrict__ cosb, const float* __restrict__ sinb, float* __restrict__ query)
{
    const int b = blockIdx.x, t = threadIdx.x;
#pragma unroll
    for (int j=0;j<4;++j){
        int item = j*256+t;
        int h = item>>5, i = item&31;
        const float* qp = q + ((size_t)b*32+h)*192 + 128;
        float x1 = qp[2*i], x2 = qp[2*i+1];
        float c = cosb[b*32+i], s = sinb[b*32+i];
        float* o = query + ((size_t)b*32+h)*576;
        o[512+i] = x1*c - x2*s;
        o[544+i] = x2*c + x1*s;
    }
}

// ---------- flash decode attention, bf16 MFMA 16x16x32
// 4 waves: QK^T quadrant (ht=w&1, kt=w>>1); PV: h-tile = w&1, r-range = (w>>1)*256.
// LDS: Krows[32][576] bf16 (XOR swz), Vt[512][32] bf16 (keys-fastest, XOR swz),
//      S_s[32][33] f32, P_s[32][40] bf16, alpha_s[32].  Total 76544 B -> 2 blocks/CU.
__global__ __launch_bounds__(256,2) void attn_mfma(const float* __restrict__ query,
        const float* __restrict__ kv, const float* __restrict__ latent,
        const int* __restrict__ slots, const int* __restrict__ seq_lens,
        float* __restrict__ Opart, float* __restrict__ Mpart, float* __restrict__ Lpart)
{
    __shared__ unsigned short Krows[32*576];
    __shared__ unsigned short Vt[512*32];
    __shared__ float S_s[32*33];
    __shared__ unsigned short P_s[32*40];
    __shared__ float alpha_s[32];

    const int b = blockIdx.y, sp = blockIdx.x;
    const int tid = threadIdx.x;
    const int w = tid>>6, l = tid&63;
    const int lm = l&15, lg = l>>4;
    const int ht = w&1, kt = w>>1;
    const int seqlen = seq_lens[b];
    const int slot = slots[b];
    const int k0 = sp*512;
    const int myh = tid>>3, s5 = tid&7;   // softmax: 8 threads per head

    // ---- Q fragments (A operand): head = ht*16+lm, k-slice (lg*8) of each 32-chunk
    bf16x8 qf[18];
    {
        const float* qrow = query + ((size_t)b*32 + ht*16 + lm)*576;
#pragma unroll
        for (int s=0;s<18;++s){
            int d0 = s*32 + lg*8;
            float4 a = *(const float4*)(qrow + d0);
            float4 c = *(const float4*)(qrow + d0 + 4);
            union{uint4 u; bf16x8 v;} cv;
            cv.u.x=pack2(a.x,a.y); cv.u.y=pack2(a.z,a.w);
            cv.u.z=pack2(c.x,c.y); cv.u.w=pack2(c.z,c.w);
            qf[s]=cv.v;
        }
    }

    float4 ld[18];
    auto load_tile = [&](int tt){
#pragma unroll
        for (int c=0;c<9;++c){
            int off = c*2048 + tid*8;
            int row = off/576, col = off - row*576;
            int gk = k0 + tt*32 + row;
            const float* src = (gk==slot) ? (latent + (size_t)b*576 + col)
                                          : (kv + ((size_t)b*KCTX + gk)*576 + col);
            ld[2*c]   = *(const float4*)src;
            ld[2*c+1] = *(const float4*)(src+4);
        }
    };
    auto write_tile = [&](){
#pragma unroll
        for (int c=0;c<9;++c){
            int off = c*2048 + tid*8;
            int row = off/576, col = off - row*576;
            float4 a = ld[2*c], d = ld[2*c+1];
            uint4 u;
            u.x=pack2(a.x,a.y); u.y=pack2(a.z,a.w);
            u.z=pack2(d.x,d.y); u.w=pack2(d.z,d.w);
            *(uint4*)(Krows + row*576 + (col ^ ((row&7)<<3))) = u;
        }
    };

    f32x4 oacc[16];
#pragma unroll
    for (int i=0;i<16;++i){ oacc[i][0]=0.f; oacc[i][1]=0.f; oacc[i][2]=0.f; oacc[i][3]=0.f; }
    float m_run = NEGINF, l_run = 0.f;

    load_tile(0); write_tile(); __syncthreads();

    for (int tt=0; tt<16; ++tt){
        // ---- transpose pass: Krows(d<512) -> Vt[d][key]
#pragma unroll
        for (int i=0;i<8;++i){
            int d = ((i&1)<<8) + tid;
            int kq = (i>>1)<<3;
            unsigned short v0 = Krows[(kq+0)*576 + (d ^ (((kq+0)&7)<<3))];
            unsigned short v1 = Krows[(kq+1)*576 + (d ^ (((kq+1)&7)<<3))];
            unsigned short v2 = Krows[(kq+2)*576 + (d ^ (((kq+2)&7)<<3))];
            unsigned short v3 = Krows[(kq+3)*576 + (d ^ (((kq+3)&7)<<3))];
            unsigned short v4 = Krows[(kq+4)*576 + (d ^ (((kq+4)&7)<<3))];
            unsigned short v5 = Krows[(kq+5)*576 + (d ^ (((kq+5)&7)<<3))];
            unsigned short v6 = Krows[(kq+6)*576 + (d ^ (((kq+6)&7)<<3))];
            unsigned short v7 = Krows[(kq+7)*576 + (d ^ (((kq+7)&7)<<3))];
            uint4 u;
            u.x = (unsigned)v0 | ((unsigned)v1<<16);
            u.y = (unsigned)v2 | ((unsigned)v3<<16);
            u.z = (unsigned)v4 | ((unsigned)v5<<16);
            u.w = (unsigned)v6 | ((unsigned)v7<<16);
            *(uint4*)(Vt + d*32 + (kq ^ ((d&3)<<3))) = u;
        }
        // ---- QK^T: D[h,k] quadrant (ht,kt)
        {
            f32x4 sacc; sacc[0]=0.f; sacc[1]=0.f; sacc[2]=0.f; sacc[3]=0.f;
            const int key = kt*16 + lm;
            const unsigned short* kb = Krows + key*576;
            const int sw = (key&7)<<3;
#pragma unroll
            for (int s=0;s<18;++s){
                int dof = s*32 + lg*8;
                bf16x8 bv = *(const bf16x8*)(kb + (dof ^ sw));
                sacc = __builtin_amdgcn_mfma_f32_16x16x32_bf16(qf[s], bv, sacc, 0,0,0);
            }
            int hrow = ht*16 + (lg<<2);
#pragma unroll
            for (int r=0;r<4;++r) S_s[(hrow+r)*33 + key] = sacc[r];
        }
        __syncthreads();

        // ---- online softmax: 8 threads per head, keys s5+8j
        {
            const int kbase = k0 + tt*32;
            float sc[4];
#pragma unroll
            for (int j=0;j<4;++j){
                int k = s5 + 8*j;
                float v = S_s[myh*33 + k]*SM_SCALE;
                sc[j] = (kbase + k < seqlen) ? v : NEGINF;
            }
            float tmax = fmaxf(fmaxf(sc[0],sc[1]),fmaxf(sc[2],sc[3]));
            tmax = fmaxf(tmax, __shfl_xor(tmax,1));
            tmax = fmaxf(tmax, __shfl_xor(tmax,2));
            tmax = fmaxf(tmax, __shfl_xor(tmax,4));
            float mnew = fmaxf(m_run, tmax);
            float al = __expf(m_run - mnew);
            float ps = 0.f;
#pragma unroll
            for (int j=0;j<4;++j){
                float pv = (sc[j] > 0.5f*NEGINF) ? __expf(sc[j]-mnew) : 0.f;
                ps += pv;
                P_s[myh*40 + s5 + 8*j] = f2bf(pv);
            }
            ps += __shfl_xor(ps,1); ps += __shfl_xor(ps,2); ps += __shfl_xor(ps,4);
            l_run = l_run*al + ps;
            m_run = mnew;
            if (s5==0) alpha_s[myh] = al;
        }
        __syncthreads();

        // ---- PV: D[h,r], h-tile = ht, r-range = kt*256
        {
            float al4[4];
#pragma unroll
            for (int r=0;r<4;++r) al4[r] = alpha_s[ht*16 + (lg<<2) + r];
            bf16x8 pa = *(const bf16x8*)(P_s + (ht*16+lm)*40 + lg*8);
#pragma unroll
            for (int nt=0;nt<16;++nt){
                f32x4 o = oacc[nt];
                o[0]*=al4[0]; o[1]*=al4[1]; o[2]*=al4[2]; o[3]*=al4[3];
                int r = kt*256 + nt*16 + lm;
                bf16x8 bv = *(const bf16x8*)(Vt + r*32 + ((lg*8) ^ ((r&3)<<3)));
                oacc[nt] = __builtin_amdgcn_mfma_f32_16x16x32_bf16(pa, bv, o, 0,0,0);
            }
        }
        if (tt < 15){ load_tile(tt+1); write_tile(); }
        __syncthreads();
    }

    // ---- epilogue
    const int obase = (b*NSPLIT+sp)*32;
#pragma unroll
    for (int nt=0;nt<16;++nt){
        int r = kt*256 + nt*16 + lm;
#pragma unroll
        for (int q=0;q<4;++q){
            int h = ht*16 + (lg<<2) + q;
            Opart[((size_t)(obase+h))*512 + r] = oacc[nt][q];
        }
    }
    if (s5==0){ Mpart[obase+myh]=m_run; Lpart[obase+myh]=l_run; }
}

// ---------- merge NSPLIT flash partials -> attn[b][h][512]
__global__ __launch_bounds__(256) void merge_attn(const float* __restrict__ Opart,
        const float* __restrict__ Mpart, const float* __restrict__ Lpart, float* __restrict__ attn)
{
    const int bh = blockIdx.x;
    const int b = bh>>5, h = bh&31;
    const int t = threadIdx.x;
    float m[NSPLIT], lw[NSPLIT];
    float M = NEGINF;
#pragma unroll
    for (int s=0;s<NSPLIT;++s){ m[s] = Mpart[(b*NSPLIT+s)*32 + h]; M = fmaxf(M,m[s]); }
    float L = 0.f;
#pragma unroll
    for (int s=0;s<NSPLIT;++s){ lw[s] = __expf(m[s]-M); L += lw[s]*Lpart[(b*NSPLIT+s)*32+h]; }
    float inv = 1.f/L;
#pragma unroll
    for (int j=0;j<2;++j){
        int r = j*256+t;
        float o = 0.f;
#pragma unroll
        for (int s=0;s<NSPLIT;++s)
            o += lw[s]*Opart[((size_t)((b*NSPLIT+s)*32) + h)*512 + r];
        attn[((size_t)b*32+h)*512 + r] = o*inv;
    }
}

// ---------- out[b][h*128+v] = sum_r attn[b][h][r]*w_uv[h][r][v]
__global__ __launch_bounds__(128) void av_uv(const float* __restrict__ attn,
        const float* __restrict__ wuv, float* __restrict__ ao)
{
    const int h = blockIdx.x, bg = blockIdx.y, t = threadIdx.x;
    __shared__ float a_s[8*512];
#pragma unroll
    for (int i=0;i<32;++i){
        int idx = i*128+t;
        int bb = idx>>9, rr = idx&511;
        a_s[idx] = attn[((size_t)(bg*8+bb)*32 + h)*512 + rr];
    }
    __syncthreads();
    float acc[8];
#pragma unroll
    for (int i=0;i<8;++i) acc[i]=0.f;
    const float* wp = wuv + (size_t)h*512*128 + t;
    for (int r0=0;r0<512;r0+=4){
        float w0 = wp[(size_t)(r0+0)*128];
        float w1 = wp[(size_t)(r0+1)*128];
        float w2 = wp[(size_t)(r0+2)*128];
        float w3 = wp[(size_t)(r0+3)*128];
#pragma unroll
        for (int bb=0;bb<8;++bb){
            const float4 a = *(const float4*)(a_s + bb*512 + r0);
            acc[bb] = fmaf(a.x,w0,fmaf(a.y,w1,fmaf(a.z,w2,fmaf(a.w,w3,acc[bb]))));
        }
    }
#pragma unroll
    for (int bb=0;bb<8;++bb) ao[(size_t)(bg*8+bb)*4096 + h*128 + t] = acc[bb];
}

extern "C" void kernel_launch(void* const* d_in, const int* in_sizes, int n_in,
                              void* d_out, int out_size, void* d_ws, size_t ws_size,
                              hipStream_t stream)
{
    const float* hidden = (const float*)d_in[0];
    const float* cosb   = (const float*)d_in[1];
    const float* sinb   = (const float*)d_in[2];
    const float* kv     = (const float*)d_in[3];
    const float* w_q_a  = (const float*)d_in[4];
    const float* q_ln   = (const float*)d_in[5];
    const float* w_q_b  = (const float*)d_in[6];
    const float* w_kv_a = (const float*)d_in[7];
    const float* kv_ln  = (const float*)d_in[8];
    const float* w_uk_t = (const float*)d_in[9];
    const float* w_uv   = (const float*)d_in[10];
    const float* w_o    = (const float*)d_in[11];
    const int* slots    = (const int*)d_in[12];
    const int* seqlens  = (const int*)d_in[13];
    float* out = (float*)d_out;

    float* W = (float*)d_ws;
    float* P      = W;                  // 8,388,608 f32 (partials; aliases Opart)
    float* q_c    = W + 8388608;
    float* q      = W + 8486912;
    float* latent = W + 8880128;
    float* query  = W + 8916992;
    float* Mp     = W + 10096640;
    float* Lp     = W + 10113024;
    float* attn   = W + 10129408;
    float* ao     = W + 11177984;

    hipLaunchKernelGGL(gemm64_part, dim3(6,28), dim3(256), 0, stream, hidden, w_q_a, P, 1536, 7168);
    hipLaunchKernelGGL(reduce_rms_qc, dim3(64), dim3(256), 0, stream, P, q_ln, q_c);
    hipLaunchKernelGGL(gemm64_part, dim3(24,6), dim3(256), 0, stream, q_c, w_q_b, P, 6144, 1536);
    hipLaunchKernelGGL(reduce_sum, dim3(1536), dim3(256), 0, stream, P, q, 6, 6144);
    hipLaunchKernelGGL(gemm64_part, dim3(3,28), dim3(256), 0, stream, hidden, w_kv_a, P, 576, 7168);
    hipLaunchKernelGGL(reduce_kv_rope, dim3(64), dim3(256), 0, stream, P, kv_ln, cosb, sinb, latent);
    hipLaunchKernelGGL(qlnope_query, dim3(32,2), dim3(256), 0, stream, q, w_uk_t, query);
    hipLaunchKernelGGL(rope_q, dim3(64), dim3(256), 0, stream, q, cosb, sinb, query);
    hipLaunchKernelGGL(attn_mfma, dim3(NSPLIT,64), dim3(256), 0, stream,
                       query, kv, latent, slots, seqlens, P, Mp, Lp);
    hipLaunchKernelGGL(merge_attn, dim3(2048), dim3(256), 0, stream, P, Mp, Lp, attn);
    hipLaunchKernelGGL(av_uv, dim3(32,8), dim3(128), 0, stream, attn, w_uv, ao);
    hipLaunchKernelGGL(gemm64_part, dim3(28,16), dim3(256), 0, stream, ao, w_o, P, 7168, 4096);
    hipLaunchKernelGGL(reduce_sum, dim3(1792), dim3(256), 0, stream, P, out, 16, 7168);
}

// Round 4
// 461.151 us; speedup vs baseline: 2.9582x; 1.9508x over previous
//
#include <hip/hip_runtime.h>
#include <stdint.h>

#define NB 64
#define NH 32
#define KCTX 4096
#define HID 7168
#define QLORA 1536
#define KVL 512
#define DTOT 576
#define NSPLIT 8
#define SM_SCALE 0.07216878364870323f  // 1/sqrt(192)
#define NEGINF (-3.0e38f)

typedef __attribute__((ext_vector_type(4))) float f32x4;
typedef __attribute__((ext_vector_type(8))) __bf16 bf16x8;

static __device__ __forceinline__ unsigned short f2bf(float f){
    union{float f;unsigned i;}x; x.f=f;
    unsigned r = x.i + 0x7fffu + ((x.i>>16)&1u);
    return (unsigned short)(r>>16);
}
static __device__ __forceinline__ float bf2f(unsigned short h){
    union{unsigned i;float f;}x; x.i=((unsigned)h)<<16; return x.f;
}
static __device__ __forceinline__ unsigned pack2(float a, float b){
    return (unsigned)f2bf(a) | ((unsigned)f2bf(b)<<16);
}

// ---------- pack A[64][K] fp32 -> frag-ready bf16 hi/lo words: word idx = (k>>3)*64+m
__global__ __launch_bounds__(256) void pack_a(const float* __restrict__ A,
        unsigned short* __restrict__ Hi, unsigned short* __restrict__ Lo, int K)
{
    int idx = blockIdx.x*256 + threadIdx.x;   // word index over 64*K/8
    int m = idx & 63, kb = idx >> 6;
    const float* src = A + (size_t)m*K + kb*8;
    float v[8];
    *(float4*)(v)   = *(const float4*)(src);
    *(float4*)(v+4) = *(const float4*)(src+4);
    unsigned short h[8], l[8];
#pragma unroll
    for (int j=0;j<8;++j){
        h[j] = f2bf(v[j]);
        l[j] = f2bf(v[j] - bf2f(h[j]));
    }
    uint4 uh, ul;
    uh.x=(unsigned)h[0]|((unsigned)h[1]<<16); uh.y=(unsigned)h[2]|((unsigned)h[3]<<16);
    uh.z=(unsigned)h[4]|((unsigned)h[5]<<16); uh.w=(unsigned)h[6]|((unsigned)h[7]<<16);
    ul.x=(unsigned)l[0]|((unsigned)l[1]<<16); ul.y=(unsigned)l[2]|((unsigned)l[3]<<16);
    ul.z=(unsigned)l[4]|((unsigned)l[5]<<16); ul.w=(unsigned)l[6]|((unsigned)l[7]<<16);
    *(uint4*)(Hi + (size_t)idx*8) = uh;
    *(uint4*)(Lo + (size_t)idx*8) = ul;
}

// ---------- MFMA skinny GEMM: P[s][64][N] = A[64][Ks]@W[Ks][N], split-bf16 (hi/lo)
// grid (N/64, splits); block 256 = 4 waves; wave w owns m-tile w, all 4 n-tiles.
__global__ __launch_bounds__(256) void gemm_mfma(
        const unsigned short* __restrict__ Ahi, const unsigned short* __restrict__ Alo,
        const float* __restrict__ Wm, float* __restrict__ P, int N, int ksteps)
{
    __shared__ unsigned short Ah[2048], Al[2048], Bh[2048], Bl[2048];
    const int tid = threadIdx.x;
    const int w = tid>>6, l = tid&63, lm = l&15, lg = l>>4;
    const int n0 = blockIdx.x*64;
    const int s  = blockIdx.y;
    const int mn = tid&63, ks = tid>>6;            // staging role
    const int widx = ((mn>>4)*64 + ks*16 + (mn&15));

    f32x4 acc[4];
#pragma unroll
    for (int i=0;i<4;++i){ acc[i][0]=0.f; acc[i][1]=0.f; acc[i][2]=0.f; acc[i][3]=0.f; }

    for (int t=0; t<ksteps; ++t){
        const int k0 = (s*ksteps + t)*32;
        // A: frag-ready 16B loads
        size_t gidx = (size_t)((k0>>3) + ks)*64 + mn;
        uint4 ah4 = *(const uint4*)(Ahi + gidx*8);
        uint4 al4 = *(const uint4*)(Alo + gidx*8);
        // W: k-gather 8 scalars, convert to hi/lo
        const float* wp = Wm + (size_t)(k0 + ks*8)*N + n0 + mn;
        float wv[8];
#pragma unroll
        for (int j=0;j<8;++j) wv[j] = wp[(size_t)j*N];
        unsigned short h[8], lo[8];
#pragma unroll
        for (int j=0;j<8;++j){
            h[j] = f2bf(wv[j]);
            lo[j] = f2bf(wv[j] - bf2f(h[j]));
        }
        uint4 bh4, bl4;
        bh4.x=(unsigned)h[0]|((unsigned)h[1]<<16); bh4.y=(unsigned)h[2]|((unsigned)h[3]<<16);
        bh4.z=(unsigned)h[4]|((unsigned)h[5]<<16); bh4.w=(unsigned)h[6]|((unsigned)h[7]<<16);
        bl4.x=(unsigned)lo[0]|((unsigned)lo[1]<<16); bl4.y=(unsigned)lo[2]|((unsigned)lo[3]<<16);
        bl4.z=(unsigned)lo[4]|((unsigned)lo[5]<<16); bl4.w=(unsigned)lo[6]|((unsigned)lo[7]<<16);

        __syncthreads();    // previous iter's frag reads done
        *(uint4*)(Ah + widx*8) = ah4;
        *(uint4*)(Al + widx*8) = al4;
        *(uint4*)(Bh + widx*8) = bh4;
        *(uint4*)(Bl + widx*8) = bl4;
        __syncthreads();

        const int fa = (w*64 + lg*16 + lm)*8;
        bf16x8 fah = *(const bf16x8*)(Ah + fa);
        bf16x8 fal = *(const bf16x8*)(Al + fa);
#pragma unroll
        for (int nt=0;nt<4;++nt){
            const int fb = (nt*64 + lg*16 + lm)*8;
            bf16x8 fbh = *(const bf16x8*)(Bh + fb);
            bf16x8 fbl = *(const bf16x8*)(Bl + fb);
            acc[nt] = __builtin_amdgcn_mfma_f32_16x16x32_bf16(fah, fbh, acc[nt], 0,0,0);
            acc[nt] = __builtin_amdgcn_mfma_f32_16x16x32_bf16(fal, fbh, acc[nt], 0,0,0);
            acc[nt] = __builtin_amdgcn_mfma_f32_16x16x32_bf16(fah, fbl, acc[nt], 0,0,0);
        }
    }
    // epilogue: P[s][m][n]
#pragma unroll
    for (int nt=0;nt<4;++nt){
        int n = n0 + nt*16 + lm;
#pragma unroll
        for (int r=0;r<4;++r){
            int m = w*16 + lg*4 + r;
            P[((size_t)s*64 + m)*N + n] = acc[nt][r];
        }
    }
}

// ---------- reduce S partials + rmsnorm -> q_c[64][1536]
__global__ __launch_bounds__(256) void reduce_rms_qc(const float* __restrict__ P,
        const float* __restrict__ w, float* __restrict__ out, int S)
{
    const int b = blockIdx.x, t = threadIdx.x;
    float v[6]; float ss = 0.f;
#pragma unroll
    for (int j=0;j<6;++j){
        int n = j*256 + t;
        float s = 0.f;
        for (int sp=0; sp<S; ++sp) s += P[((size_t)sp*64+b)*1536 + n];
        v[j] = s; ss += s*s;
    }
    __shared__ float red[4];
#pragma unroll
    for (int off=32; off>=1; off>>=1) ss += __shfl_xor(ss, off, 64);
    if ((t&63)==0) red[t>>6] = ss;
    __syncthreads();
    float tot = red[0]+red[1]+red[2]+red[3];
    float rs = rsqrtf(tot/1536.f + 1e-6f);
#pragma unroll
    for (int j=0;j<6;++j){
        int n = j*256+t;
        out[(size_t)b*1536 + n] = v[j]*rs*w[n];
    }
}

// ---------- generic partial reduce
__global__ __launch_bounds__(256) void reduce_sum(const float* __restrict__ P,
        float* __restrict__ out, int S, int N)
{
    int i = blockIdx.x*256 + threadIdx.x;
    int b = i / N, n = i - b*N;
    float s = 0.f;
    for (int sp=0; sp<S; ++sp) s += P[((size_t)sp*64+b)*N + n];
    out[i] = s;
}

// ---------- reduce ckv partials + rmsnorm(512) + rope(last 64) -> latent[64][576]
__global__ __launch_bounds__(256) void reduce_kv_rope(const float* __restrict__ P,
        const float* __restrict__ w, const float* __restrict__ cosb, const float* __restrict__ sinb,
        float* __restrict__ latent, int S)
{
    const int b = blockIdx.x, t = threadIdx.x;
    __shared__ float vals[576];
    __shared__ float red[4];
    float ss = 0.f;
    for (int j=0;j<3;++j){
        int n = j*256+t;
        if (n < 576){
            float s=0.f;
            for (int sp=0;sp<S;++sp) s += P[((size_t)sp*64+b)*576 + n];
            vals[n]=s;
            if (n<512) ss += s*s;
        }
    }
#pragma unroll
    for (int off=32; off>=1; off>>=1) ss += __shfl_xor(ss, off, 64);
    if ((t&63)==0) red[t>>6]=ss;
    __syncthreads();
    float tot = red[0]+red[1]+red[2]+red[3];
    float rs = rsqrtf(tot/512.f + 1e-6f);
    for (int j=0;j<3;++j){
        int n = j*256+t;
        if (n<576){
            float o;
            if (n < 512) o = vals[n]*rs*w[n];
            else if (n < 544){ int i=n-512; o = vals[512+2*i]*cosb[b*32+i] - vals[513+2*i]*sinb[b*32+i]; }
            else            { int i=n-544; o = vals[513+2*i]*cosb[b*32+i] + vals[512+2*i]*sinb[b*32+i]; }
            latent[(size_t)b*576 + n] = o;
        }
    }
}

// ---------- ql_nope: query[b][h][r] = sum_n q[b][h][n]*w_uk_t[h][n][r]   (r<512)
__global__ __launch_bounds__(256) void qlnope_query(const float* __restrict__ q,
        const float* __restrict__ wukt, float* __restrict__ query)
{
    const int h = blockIdx.x;
    const int t = threadIdx.x;
    const int r = blockIdx.y*256 + t;
    __shared__ float qn[64*128];
    float acc[64];
#pragma unroll
    for (int i=0;i<64;++i) acc[i]=0.f;
#pragma unroll
    for (int i=0;i<32;++i){
        int idx = i*256+t;
        int bb = idx>>7, nn = idx&127;
        qn[idx] = q[((size_t)bb*32+h)*192 + nn];
    }
    __syncthreads();
    const float* wp = wukt + (size_t)h*128*512 + r;
    for (int n0=0;n0<128;n0+=4){
        float w0 = wp[(size_t)(n0+0)*512];
        float w1 = wp[(size_t)(n0+1)*512];
        float w2 = wp[(size_t)(n0+2)*512];
        float w3 = wp[(size_t)(n0+3)*512];
#pragma unroll
        for (int bb=0;bb<64;++bb){
            const float4 a = *(const float4*)(qn + bb*128 + n0);
            acc[bb] = fmaf(a.x,w0,fmaf(a.y,w1,fmaf(a.z,w2,fmaf(a.w,w3,acc[bb]))));
        }
    }
#pragma unroll
    for (int bb=0;bb<64;++bb) query[((size_t)bb*32+h)*576 + r] = acc[bb];
}

// ---------- rope for q_pe -> query[b][h][512..575]
__global__ __launch_bounds__(256) void rope_q(const float* __restrict__ q,
        const float* __restrict__ cosb, const float* __restrict__ sinb, float* __restrict__ query)
{
    const int b = blockIdx.x, t = threadIdx.x;
#pragma unroll
    for (int j=0;j<4;++j){
        int item = j*256+t;
        int h = item>>5, i = item&31;
        const float* qp = q + ((size_t)b*32+h)*192 + 128;
        float x1 = qp[2*i], x2 = qp[2*i+1];
        float c = cosb[b*32+i], s = sinb[b*32+i];
        float* o = query + ((size_t)b*32+h)*576;
        o[512+i] = x1*c - x2*s;
        o[544+i] = x2*c + x1*s;
    }
}

// ---------- flash decode attention, bf16 MFMA 16x16x32
__global__ __launch_bounds__(256,2) void attn_mfma(const float* __restrict__ query,
        const float* __restrict__ kv, const float* __restrict__ latent,
        const int* __restrict__ slots, const int* __restrict__ seq_lens,
        float* __restrict__ Opart, float* __restrict__ Mpart, float* __restrict__ Lpart)
{
    __shared__ unsigned short Krows[32*576];
    __shared__ unsigned short Vt[512*32];
    __shared__ float S_s[32*33];
    __shared__ unsigned short P_s[32*40];
    __shared__ float alpha_s[32];

    const int b = blockIdx.y, sp = blockIdx.x;
    const int tid = threadIdx.x;
    const int w = tid>>6, l = tid&63;
    const int lm = l&15, lg = l>>4;
    const int ht = w&1, kt = w>>1;
    const int seqlen = seq_lens[b];
    const int slot = slots[b];
    const int k0 = sp*512;
    const int myh = tid>>3, s5 = tid&7;

    bf16x8 qf[18];
    {
        const float* qrow = query + ((size_t)b*32 + ht*16 + lm)*576;
#pragma unroll
        for (int s=0;s<18;++s){
            int d0 = s*32 + lg*8;
            float4 a = *(const float4*)(qrow + d0);
            float4 c = *(const float4*)(qrow + d0 + 4);
            union{uint4 u; bf16x8 v;} cv;
            cv.u.x=pack2(a.x,a.y); cv.u.y=pack2(a.z,a.w);
            cv.u.z=pack2(c.x,c.y); cv.u.w=pack2(c.z,c.w);
            qf[s]=cv.v;
        }
    }

    float4 ld[18];
    auto load_tile = [&](int tt){
#pragma unroll
        for (int c=0;c<9;++c){
            int off = c*2048 + tid*8;
            int row = off/576, col = off - row*576;
            int gk = k0 + tt*32 + row;
            const float* src = (gk==slot) ? (latent + (size_t)b*576 + col)
                                          : (kv + ((size_t)b*KCTX + gk)*576 + col);
            ld[2*c]   = *(const float4*)src;
            ld[2*c+1] = *(const float4*)(src+4);
        }
    };
    auto write_tile = [&](){
#pragma unroll
        for (int c=0;c<9;++c){
            int off = c*2048 + tid*8;
            int row = off/576, col = off - row*576;
            float4 a = ld[2*c], d = ld[2*c+1];
            uint4 u;
            u.x=pack2(a.x,a.y); u.y=pack2(a.z,a.w);
            u.z=pack2(d.x,d.y); u.w=pack2(d.z,d.w);
            *(uint4*)(Krows + row*576 + (col ^ ((row&7)<<3))) = u;
        }
    };

    f32x4 oacc[16];
#pragma unroll
    for (int i=0;i<16;++i){ oacc[i][0]=0.f; oacc[i][1]=0.f; oacc[i][2]=0.f; oacc[i][3]=0.f; }
    float m_run = NEGINF, l_run = 0.f;

    load_tile(0); write_tile(); __syncthreads();

    for (int tt=0; tt<16; ++tt){
        // ---- transpose Krows(d<512) -> Vt[d][keypos]; granule swizzle (kq>>3)^((d>>1)&3)
#pragma unroll
        for (int i=0;i<8;++i){
            int d = ((i&1)<<8) + tid;
            int kq = (i>>1)<<3;
            unsigned short v0 = Krows[(kq+0)*576 + (d ^ (((kq+0)&7)<<3))];
            unsigned short v1 = Krows[(kq+1)*576 + (d ^ (((kq+1)&7)<<3))];
            unsigned short v2 = Krows[(kq+2)*576 + (d ^ (((kq+2)&7)<<3))];
            unsigned short v3 = Krows[(kq+3)*576 + (d ^ (((kq+3)&7)<<3))];
            unsigned short v4 = Krows[(kq+4)*576 + (d ^ (((kq+4)&7)<<3))];
            unsigned short v5 = Krows[(kq+5)*576 + (d ^ (((kq+5)&7)<<3))];
            unsigned short v6 = Krows[(kq+6)*576 + (d ^ (((kq+6)&7)<<3))];
            unsigned short v7 = Krows[(kq+7)*576 + (d ^ (((kq+7)&7)<<3))];
            uint4 u;
            u.x = (unsigned)v0 | ((unsigned)v1<<16);
            u.y = (unsigned)v2 | ((unsigned)v3<<16);
            u.z = (unsigned)v4 | ((unsigned)v5<<16);
            u.w = (unsigned)v6 | ((unsigned)v7<<16);
            *(uint4*)(Vt + d*32 + ((((kq>>3) ^ ((d>>1)&3)))<<3)) = u;
        }
        // ---- QK^T
        {
            f32x4 sacc; sacc[0]=0.f; sacc[1]=0.f; sacc[2]=0.f; sacc[3]=0.f;
            const int key = kt*16 + lm;
            const unsigned short* kb = Krows + key*576;
            const int sw = (key&7)<<3;
#pragma unroll
            for (int s=0;s<18;++s){
                int dof = s*32 + lg*8;
                bf16x8 bv = *(const bf16x8*)(kb + (dof ^ sw));
                sacc = __builtin_amdgcn_mfma_f32_16x16x32_bf16(qf[s], bv, sacc, 0,0,0);
            }
            int hrow = ht*16 + (lg<<2);
#pragma unroll
            for (int r=0;r<4;++r) S_s[(hrow+r)*33 + key] = sacc[r];
        }
        __syncthreads();

        // ---- online softmax
        {
            const int kbase = k0 + tt*32;
            float sc[4];
#pragma unroll
            for (int j=0;j<4;++j){
                int k = s5 + 8*j;
                float v = S_s[myh*33 + k]*SM_SCALE;
                sc[j] = (kbase + k < seqlen) ? v : NEGINF;
            }
            float tmax = fmaxf(fmaxf(sc[0],sc[1]),fmaxf(sc[2],sc[3]));
            tmax = fmaxf(tmax, __shfl_xor(tmax,1));
            tmax = fmaxf(tmax, __shfl_xor(tmax,2));
            tmax = fmaxf(tmax, __shfl_xor(tmax,4));
            float mnew = fmaxf(m_run, tmax);
            float al = __expf(m_run - mnew);
            float ps = 0.f;
#pragma unroll
            for (int j=0;j<4;++j){
                float pv = (sc[j] > 0.5f*NEGINF) ? __expf(sc[j]-mnew) : 0.f;
                ps += pv;
                P_s[myh*40 + s5 + 8*j] = f2bf(pv);
            }
            ps += __shfl_xor(ps,1); ps += __shfl_xor(ps,2); ps += __shfl_xor(ps,4);
            l_run = l_run*al + ps;
            m_run = mnew;
            if (s5==0) alpha_s[myh] = al;
        }
        __syncthreads();

        // ---- PV
        {
            float al4[4];
#pragma unroll
            for (int r=0;r<4;++r) al4[r] = alpha_s[ht*16 + (lg<<2) + r];
            bf16x8 pa = *(const bf16x8*)(P_s + (ht*16+lm)*40 + lg*8);
#pragma unroll
            for (int nt=0;nt<16;++nt){
                f32x4 o = oacc[nt];
                o[0]*=al4[0]; o[1]*=al4[1]; o[2]*=al4[2]; o[3]*=al4[3];
                int r = kt*256 + nt*16 + lm;
                bf16x8 bv = *(const bf16x8*)(Vt + r*32 + ((lg ^ ((r>>1)&3))<<3));
                oacc[nt] = __builtin_amdgcn_mfma_f32_16x16x32_bf16(pa, bv, o, 0,0,0);
            }
        }
        if (tt < 15){ load_tile(tt+1); write_tile(); }
        __syncthreads();
    }

    // ---- write partials
    const int obase = (b*NSPLIT+sp)*32;
#pragma unroll
    for (int nt=0;nt<16;++nt){
        int r = kt*256 + nt*16 + lm;
#pragma unroll
        for (int q=0;q<4;++q){
            int h = ht*16 + (lg<<2) + q;
            Opart[((size_t)(obase+h))*512 + r] = oacc[nt][q];
        }
    }
    if (s5==0){ Mpart[obase+myh]=m_run; Lpart[obase+myh]=l_run; }
}

// ---------- merge NSPLIT flash partials -> attn[b][h][512]
__global__ __launch_bounds__(256) void merge_attn(const float* __restrict__ Opart,
        const float* __restrict__ Mpart, const float* __restrict__ Lpart, float* __restrict__ attn)
{
    const int bh = blockIdx.x;
    const int b = bh>>5, h = bh&31;
    const int t = threadIdx.x;
    float m[NSPLIT], lw[NSPLIT];
    float M = NEGINF;
#pragma unroll
    for (int s=0;s<NSPLIT;++s){ m[s] = Mpart[(b*NSPLIT+s)*32 + h]; M = fmaxf(M,m[s]); }
    float L = 0.f;
#pragma unroll
    for (int s=0;s<NSPLIT;++s){ lw[s] = __expf(m[s]-M); L += lw[s]*Lpart[(b*NSPLIT+s)*32+h]; }
    float inv = 1.f/L;
#pragma unroll
    for (int j=0;j<2;++j){
        int r = j*256+t;
        float o = 0.f;
#pragma unroll
        for (int s=0;s<NSPLIT;++s)
            o += lw[s]*Opart[((size_t)((b*NSPLIT+s)*32) + h)*512 + r];
        attn[((size_t)b*32+h)*512 + r] = o*inv;
    }
}

// ---------- out[b][h*128+v] = sum_r attn[b][h][r]*w_uv[h][r][v]
__global__ __launch_bounds__(128) void av_uv(const float* __restrict__ attn,
        const float* __restrict__ wuv, float* __restrict__ ao)
{
    const int h = blockIdx.x, bg = blockIdx.y, t = threadIdx.x;
    __shared__ float a_s[8*512];
#pragma unroll
    for (int i=0;i<32;++i){
        int idx = i*128+t;
        int bb = idx>>9, rr = idx&511;
        a_s[idx] = attn[((size_t)(bg*8+bb)*32 + h)*512 + rr];
    }
    __syncthreads();
    float acc[8];
#pragma unroll
    for (int i=0;i<8;++i) acc[i]=0.f;
    const float* wp = wuv + (size_t)h*512*128 + t;
    for (int r0=0;r0<512;r0+=4){
        float w0 = wp[(size_t)(r0+0)*128];
        float w1 = wp[(size_t)(r0+1)*128];
        float w2 = wp[(size_t)(r0+2)*128];
        float w3 = wp[(size_t)(r0+3)*128];
#pragma unroll
        for (int bb=0;bb<8;++bb){
            const float4 a = *(const float4*)(a_s + bb*512 + r0);
            acc[bb] = fmaf(a.x,w0,fmaf(a.y,w1,fmaf(a.z,w2,fmaf(a.w,w3,acc[bb]))));
        }
    }
#pragma unroll
    for (int bb=0;bb<8;++bb) ao[(size_t)(bg*8+bb)*4096 + h*128 + t] = acc[bb];
}

extern "C" void kernel_launch(void* const* d_in, const int* in_sizes, int n_in,
                              void* d_out, int out_size, void* d_ws, size_t ws_size,
                              hipStream_t stream)
{
    const float* hidden = (const float*)d_in[0];
    const float* cosb   = (const float*)d_in[1];
    const float* sinb   = (const float*)d_in[2];
    const float* kv     = (const float*)d_in[3];
    const float* w_q_a  = (const float*)d_in[4];
    const float* q_ln   = (const float*)d_in[5];
    const float* w_q_b  = (const float*)d_in[6];
    const float* w_kv_a = (const float*)d_in[7];
    const float* kv_ln  = (const float*)d_in[8];
    const float* w_uk_t = (const float*)d_in[9];
    const float* w_uv   = (const float*)d_in[10];
    const float* w_o    = (const float*)d_in[11];
    const int* slots    = (const int*)d_in[12];
    const int* seqlens  = (const int*)d_in[13];
    float* out = (float*)d_out;

    float* W = (float*)d_ws;
    // all offsets in f32 units; bf16 buffers consume count/2 f32 slots
    float* P      = W;                  // 8,388,608 f32 (partials; aliases Opart)
    float* q_c    = W + 8388608;        // 98,304
    float* q      = W + 8486912;        // 393,216
    float* latent = W + 8880128;        // 36,864
    float* query  = W + 8916992;        // 1,179,648
    float* Mp     = W + 10096640;       // 16,384
    float* Lp     = W + 10113024;       // 16,384
    float* attn   = W + 10129408;       // 1,048,576
    float* ao     = W + 11177984;       // 262,144
    unsigned short* pkhid_h = (unsigned short*)(W + 11440128);   // 458,752 u16 = 229,376 f32
    unsigned short* pkhid_l = (unsigned short*)(W + 11669504);   // 229,376 f32
    unsigned short* pkqc_h  = (unsigned short*)(W + 11898880);   // 98,304 u16 = 49,152 f32
    unsigned short* pkqc_l  = (unsigned short*)(W + 11948032);   // 49,152 f32
    unsigned short* pkao_h  = (unsigned short*)(W + 11997184);   // 262,144 u16 = 131,072 f32
    unsigned short* pkao_l  = (unsigned short*)(W + 12128256);   // 131,072 f32  (end 12,259,328)

    // q branch
    hipLaunchKernelGGL(pack_a, dim3(224), dim3(256), 0, stream, hidden, pkhid_h, pkhid_l, 7168);
    hipLaunchKernelGGL(gemm_mfma, dim3(24,14), dim3(256), 0, stream, pkhid_h, pkhid_l, w_q_a, P, 1536, 16);
    hipLaunchKernelGGL(reduce_rms_qc, dim3(64), dim3(256), 0, stream, P, q_ln, q_c, 14);
    hipLaunchKernelGGL(pack_a, dim3(48), dim3(256), 0, stream, q_c, pkqc_h, pkqc_l, 1536);
    hipLaunchKernelGGL(gemm_mfma, dim3(96,3), dim3(256), 0, stream, pkqc_h, pkqc_l, w_q_b, P, 6144, 16);
    hipLaunchKernelGGL(reduce_sum, dim3(1536), dim3(256), 0, stream, P, q, 3, 6144);
    // kv branch
    hipLaunchKernelGGL(gemm_mfma, dim3(9,28), dim3(256), 0, stream, pkhid_h, pkhid_l, w_kv_a, P, 576, 8);
    hipLaunchKernelGGL(reduce_kv_rope, dim3(64), dim3(256), 0, stream, P, kv_ln, cosb, sinb, latent, 28);
    // query assembly
    hipLaunchKernelGGL(qlnope_query, dim3(32,2), dim3(256), 0, stream, q, w_uk_t, query);
    hipLaunchKernelGGL(rope_q, dim3(64), dim3(256), 0, stream, q, cosb, sinb, query);
    // attention
    hipLaunchKernelGGL(attn_mfma, dim3(NSPLIT,64), dim3(256), 0, stream,
                       query, kv, latent, slots, seqlens, P, Mp, Lp);
    hipLaunchKernelGGL(merge_attn, dim3(2048), dim3(256), 0, stream, P, Mp, Lp, attn);
    hipLaunchKernelGGL(av_uv, dim3(32,8), dim3(128), 0, stream, attn, w_uv, ao);
    // output projection
    hipLaunchKernelGGL(pack_a, dim3(128), dim3(256), 0, stream, ao, pkao_h, pkao_l, 4096);
    hipLaunchKernelGGL(gemm_mfma, dim3(112,4), dim3(256), 0, stream, pkao_h, pkao_l, w_o, P, 7168, 32);
    hipLaunchKernelGGL(reduce_sum, dim3(1792), dim3(256), 0, stream, P, out, 4, 7168);
}